// Round 1
// baseline (1224.544 us; speedup 1.0000x reference)
//
#include <hip/hip_runtime.h>

// ImpedanceAwareGCN on MI355X.
// Key algebraic rewrite: segment_sum(out[row] + imp[row]*imp_mod[col], col)
//   = scatter_add(out) [over edges] + S[v]*imp_mod[v],
//   where S[v] = sum_{e: col[e]=v} impedance[row[e]] is layer-independent.
// So per layer: dual GEMM (out = h@W+b, next_init = S*(h@Wi)) + edge scatter-add.

#define CDIM 64

__global__ void compute_S_kernel(const int* __restrict__ row, const int* __restrict__ col,
                                 const float* __restrict__ imp, float* __restrict__ S, int E) {
    int e = blockIdx.x * blockDim.x + threadIdx.x;
    if (e < E) atomicAdd(&S[col[e]], imp[row[e]]);
}

// Dual GEMM: out[n][c] = act(in)[n][:] @ W[:][c] + b[c]
//            nxt[n][c] = S[n] * (act(in)[n][:] @ Wi[:][c])   (aggregation init)
// 256 threads/block, 64 nodes/block, each thread: 1 node x 16 cols x 2 mats.
template<int K, bool RELU>
__global__ __launch_bounds__(256) void gemm_dual(const float* __restrict__ in,
        const float* __restrict__ W, const float* __restrict__ b,
        const float* __restrict__ Wi, const float* __restrict__ S,
        float* __restrict__ out, float* __restrict__ nxt, int n) {
    __shared__ float Ws[K * 64];
    __shared__ float Wis[K * 64];
    __shared__ float xs[64 * (K + 1)];   // +1 pad kills stride-K bank conflict

    for (int i = threadIdx.x; i < K * 64; i += 256) {
        Ws[i]  = W[i];
        Wis[i] = Wi[i];
    }
    int node0 = blockIdx.x * 64;
    for (int i = threadIdx.x; i < 64 * K; i += 256) {
        int nl = i / K, k = i - nl * K;
        int node = node0 + nl;
        float v = (node < n) ? in[(size_t)node0 * K + i] : 0.f;  // coalesced
        if (RELU) v = (v >= 0.f) ? v : 0.2f * v;
        xs[nl * (K + 1) + k] = v;
    }
    __syncthreads();

    int local = threadIdx.x >> 2;          // node within block, 0..63
    int c0    = (threadIdx.x & 3) << 4;    // column group start, 0/16/32/48
    int node  = node0 + local;

    float acc[16], acci[16];
#pragma unroll
    for (int j = 0; j < 16; ++j) { acc[j] = 0.f; acci[j] = 0.f; }

#pragma unroll 4
    for (int k = 0; k < K; ++k) {
        float xv = xs[local * (K + 1) + k];
        const float* wr  = &Ws[k * 64 + c0];
        const float* wir = &Wis[k * 64 + c0];
#pragma unroll
        for (int j = 0; j < 16; ++j) {
            acc[j]  = fmaf(xv, wr[j],  acc[j]);
            acci[j] = fmaf(xv, wir[j], acci[j]);
        }
    }

    if (node < n) {
        float sv = S[node];
        size_t base = (size_t)node * 64 + c0;
#pragma unroll
        for (int j = 0; j < 16; ++j) {
            out[base + j] = acc[j] + b[c0 + j];
            nxt[base + j] = sv * acci[j];
        }
    }
}

// Edge scatter: nxt[col[e]][c] += out[row[e]][c]. Wave-per-edge -> coalesced
// 256B gather + 256B atomic segment per edge.
__global__ __launch_bounds__(256) void scatter_kernel(const int* __restrict__ row,
        const int* __restrict__ col, const float* __restrict__ out,
        float* __restrict__ nxt, int E) {
    long long total = (long long)E * 64;
    long long stride = (long long)gridDim.x * blockDim.x;
    for (long long t = (long long)blockIdx.x * blockDim.x + threadIdx.x; t < total; t += stride) {
        int e = (int)(t >> 6);
        int c = (int)(t & 63);
        int r = row[e], v = col[e];
        atomicAdd(&nxt[(size_t)v * 64 + c], out[(size_t)r * 64 + c]);
    }
}

// Final FC: o[v] = h[v][:] @ Wfc + bfc. One wave per node.
__global__ __launch_bounds__(256) void fc_kernel(const float* __restrict__ h,
        const float* __restrict__ Wfc, const float* __restrict__ bfc,
        float* __restrict__ o, int n) {
    int node = blockIdx.x * 4 + (threadIdx.x >> 6);
    int lane = threadIdx.x & 63;
    float v = 0.f;
    if (node < n) v = h[(size_t)node * 64 + lane] * Wfc[lane];
#pragma unroll
    for (int off = 32; off; off >>= 1) v += __shfl_down(v, off, 64);
    if (node < n && lane == 0) o[node] = v + bfc[0];
}

extern "C" void kernel_launch(void* const* d_in, const int* in_sizes, int n_in,
                              void* d_out, int out_size, void* d_ws, size_t ws_size,
                              hipStream_t stream) {
    const float* x   = (const float*)d_in[0];
    const int*   ei  = (const int*)d_in[1];      // int32 (JAX x64 disabled)
    const float* imp = (const float*)d_in[2];
    const float* W1  = (const float*)d_in[3];
    const float* b1  = (const float*)d_in[4];
    const float* Wi1 = (const float*)d_in[5];
    const float* W2  = (const float*)d_in[6];
    const float* b2  = (const float*)d_in[7];
    const float* Wi2 = (const float*)d_in[8];
    const float* W3  = (const float*)d_in[9];
    const float* b3  = (const float*)d_in[10];
    const float* Wi3 = (const float*)d_in[11];
    const float* Wfc = (const float*)d_in[12];
    const float* bfc = (const float*)d_in[13];

    int n = in_sizes[0] / 32;      // 100000
    int E = in_sizes[1] / 2;       // 1600000
    const int* row = ei;
    const int* col = ei + E;

    float* S    = (float*)d_ws;
    float* bufA = S + n;
    float* bufB = bufA + (size_t)n * 64;
    float* bufC = bufB + (size_t)n * 64;
    float* outp = (float*)d_out;

    // S[v] = sum of impedance[row] over incoming edges of v (layer-independent)
    hipMemsetAsync(S, 0, (size_t)n * sizeof(float), stream);
    compute_S_kernel<<<(E + 255) / 256, 256, 0, stream>>>(row, col, imp, S, E);

    int gb = (n + 63) / 64;

    // Layer 1 (K=32, no input relu)
    gemm_dual<32, false><<<gb, 256, 0, stream>>>(x, W1, b1, Wi1, S, bufA, bufB, n);
    scatter_kernel<<<2048, 256, 0, stream>>>(row, col, bufA, bufB, E);

    // Layer 2 (K=64, leaky-relu on input)
    gemm_dual<64, true><<<gb, 256, 0, stream>>>(bufB, W2, b2, Wi2, S, bufC, bufA, n);
    scatter_kernel<<<2048, 256, 0, stream>>>(row, col, bufC, bufA, E);

    // Layer 3 (K=64, leaky-relu on input)
    gemm_dual<64, true><<<gb, 256, 0, stream>>>(bufA, W3, b3, Wi3, S, bufB, bufC, n);
    scatter_kernel<<<2048, 256, 0, stream>>>(row, col, bufB, bufC, E);

    // FC head
    fc_kernel<<<(n + 3) / 4, 256, 0, stream>>>(bufC, Wfc, bfc, outp, n);
}

// Round 2
// 508.248 us; speedup vs baseline: 2.4093x; 2.4093x over previous
//
#include <hip/hip_runtime.h>

// ImpedanceAwareGCN on MI355X.
// Algebraic rewrite: segment_sum(out[row] + imp[row]*imp_mod[col], col)
//   = scatter_add(out) + S[v]*imp_mod[v],  S[v] = sum_{e: col=v} imp[row[e]].
// R2: replace fp32 atomic scatter (fabric-write bound, 400MB atomics/layer)
// with per-node bucket lists + register-accumulating gather (reads cache).

#define CAP 64           // bucket capacity per node; Poisson(16) => P(>64) ~ 1e-18
#define MAX_OVF 65536

// ---------------- CSR-lite build: S, degree counts, edge buckets ----------------
__global__ __launch_bounds__(256) void build_kernel(const int* __restrict__ row,
        const int* __restrict__ col, const float* __restrict__ imp,
        float* __restrict__ S, int* __restrict__ cnt, int* __restrict__ bucket,
        int* __restrict__ ovf, int* __restrict__ ovf_cnt, int E) {
    int e = blockIdx.x * 256 + threadIdx.x;
    if (e >= E) return;
    int r = row[e], v = col[e];
    atomicAdd(&S[v], imp[r]);
    int pos = atomicAdd(&cnt[v], 1);
    if (pos < CAP) bucket[(size_t)v * CAP + pos] = r;
    else { int o = atomicAdd(ovf_cnt, 1); if (o < MAX_OVF) ovf[o] = e; }
}

// ---------------- Dual GEMM (unchanged from R1) ----------------
template<int K, bool RELU>
__global__ __launch_bounds__(256) void gemm_dual(const float* __restrict__ in,
        const float* __restrict__ W, const float* __restrict__ b,
        const float* __restrict__ Wi, const float* __restrict__ S,
        float* __restrict__ out, float* __restrict__ nxt, int n) {
    __shared__ float Ws[K * 64];
    __shared__ float Wis[K * 64];
    __shared__ float xs[64 * (K + 1)];

    for (int i = threadIdx.x; i < K * 64; i += 256) {
        Ws[i]  = W[i];
        Wis[i] = Wi[i];
    }
    int node0 = blockIdx.x * 64;
    for (int i = threadIdx.x; i < 64 * K; i += 256) {
        int nl = i / K, k = i - nl * K;
        int node = node0 + nl;
        float v = (node < n) ? in[(size_t)node0 * K + i] : 0.f;
        if (RELU) v = (v >= 0.f) ? v : 0.2f * v;
        xs[nl * (K + 1) + k] = v;
    }
    __syncthreads();

    int local = threadIdx.x >> 2;
    int c0    = (threadIdx.x & 3) << 4;
    int node  = node0 + local;

    float acc[16], acci[16];
#pragma unroll
    for (int j = 0; j < 16; ++j) { acc[j] = 0.f; acci[j] = 0.f; }

#pragma unroll 4
    for (int k = 0; k < K; ++k) {
        float xv = xs[local * (K + 1) + k];
        const float* wr  = &Ws[k * 64 + c0];
        const float* wir = &Wis[k * 64 + c0];
#pragma unroll
        for (int j = 0; j < 16; ++j) {
            acc[j]  = fmaf(xv, wr[j],  acc[j]);
            acci[j] = fmaf(xv, wir[j], acci[j]);
        }
    }

    if (node < n) {
        float sv = S[node];
        size_t base = (size_t)node * 64 + c0;
#pragma unroll
        for (int j = 0; j < 16; ++j) {
            out[base + j] = acc[j] + b[c0 + j];
            nxt[base + j] = sv * acci[j];
        }
    }
}

// ---------------- Gather aggregation: wave per node, register accumulate ----------------
__global__ __launch_bounds__(256) void gather_agg(const int* __restrict__ cnt,
        const int* __restrict__ bucket, const float* __restrict__ out,
        float* __restrict__ nxt, int n) {
    int v = blockIdx.x * 4 + (threadIdx.x >> 6);
    if (v >= n) return;
    int lane = threadIdx.x & 63;
    int deg = cnt[v]; if (deg > CAP) deg = CAP;
    float acc = nxt[(size_t)v * 64 + lane];
    int r_lane = (lane < deg) ? bucket[(size_t)v * CAP + lane] : 0;
    int i = 0;
    for (; i + 4 <= deg; i += 4) {
        int r0 = __shfl(r_lane, i);
        int r1 = __shfl(r_lane, i + 1);
        int r2 = __shfl(r_lane, i + 2);
        int r3 = __shfl(r_lane, i + 3);
        float a0 = out[(size_t)r0 * 64 + lane];
        float a1 = out[(size_t)r1 * 64 + lane];
        float a2 = out[(size_t)r2 * 64 + lane];
        float a3 = out[(size_t)r3 * 64 + lane];
        acc += (a0 + a1) + (a2 + a3);
    }
    for (; i < deg; ++i) {
        int r = __shfl(r_lane, i);
        acc += out[(size_t)r * 64 + lane];
    }
    nxt[(size_t)v * 64 + lane] = acc;
}

// ---------------- Overflow fallback (expected m == 0) ----------------
__global__ void ovf_scatter(const int* __restrict__ row, const int* __restrict__ col,
        const int* __restrict__ ovf, const int* __restrict__ ovf_cnt,
        const float* __restrict__ out, float* __restrict__ nxt) {
    int m = *ovf_cnt; if (m > MAX_OVF) m = MAX_OVF;
    int tid = blockIdx.x * blockDim.x + threadIdx.x;
    for (int t = tid; t < m * 64; t += gridDim.x * blockDim.x) {
        int e = ovf[t >> 6]; int c = t & 63;
        int r = row[e], v = col[e];
        atomicAdd(&nxt[(size_t)v * 64 + c], out[(size_t)r * 64 + c]);
    }
}

// ---------------- R1 fallback path (if ws too small) ----------------
__global__ void compute_S_kernel(const int* __restrict__ row, const int* __restrict__ col,
                                 const float* __restrict__ imp, float* __restrict__ S, int E) {
    int e = blockIdx.x * blockDim.x + threadIdx.x;
    if (e < E) atomicAdd(&S[col[e]], imp[row[e]]);
}

__global__ __launch_bounds__(256) void scatter_kernel(const int* __restrict__ row,
        const int* __restrict__ col, const float* __restrict__ out,
        float* __restrict__ nxt, int E) {
    long long total = (long long)E * 64;
    long long stride = (long long)gridDim.x * blockDim.x;
    for (long long t = (long long)blockIdx.x * blockDim.x + threadIdx.x; t < total; t += stride) {
        int e = (int)(t >> 6);
        int c = (int)(t & 63);
        int r = row[e], v = col[e];
        atomicAdd(&nxt[(size_t)v * 64 + c], out[(size_t)r * 64 + c]);
    }
}

// ---------------- FC head ----------------
__global__ __launch_bounds__(256) void fc_kernel(const float* __restrict__ h,
        const float* __restrict__ Wfc, const float* __restrict__ bfc,
        float* __restrict__ o, int n) {
    int node = blockIdx.x * 4 + (threadIdx.x >> 6);
    int lane = threadIdx.x & 63;
    float v = 0.f;
    if (node < n) v = h[(size_t)node * 64 + lane] * Wfc[lane];
#pragma unroll
    for (int off = 32; off; off >>= 1) v += __shfl_down(v, off, 64);
    if (node < n && lane == 0) o[node] = v + bfc[0];
}

extern "C" void kernel_launch(void* const* d_in, const int* in_sizes, int n_in,
                              void* d_out, int out_size, void* d_ws, size_t ws_size,
                              hipStream_t stream) {
    const float* x   = (const float*)d_in[0];
    const int*   ei  = (const int*)d_in[1];
    const float* imp = (const float*)d_in[2];
    const float* W1  = (const float*)d_in[3];
    const float* b1  = (const float*)d_in[4];
    const float* Wi1 = (const float*)d_in[5];
    const float* W2  = (const float*)d_in[6];
    const float* b2  = (const float*)d_in[7];
    const float* Wi2 = (const float*)d_in[8];
    const float* W3  = (const float*)d_in[9];
    const float* b3  = (const float*)d_in[10];
    const float* Wi3 = (const float*)d_in[11];
    const float* Wfc = (const float*)d_in[12];
    const float* bfc = (const float*)d_in[13];

    int n = in_sizes[0] / 32;      // 100000
    int E = in_sizes[1] / 2;       // 1600000
    const int* row = ei;
    const int* col = ei + E;

    // workspace layout
    float* S      = (float*)d_ws;                       // n
    float* bufA   = S + n;                              // n*64
    float* bufB   = bufA + (size_t)n * 64;              // n*64
    float* bufC   = bufB + (size_t)n * 64;              // n*64
    int*   cnt    = (int*)(bufC + (size_t)n * 64);      // n
    int*   ovfc   = cnt + n;                            // 16 (padded)
    int*   ovf    = ovfc + 16;                          // MAX_OVF
    int*   bucket = ovf + MAX_OVF;                      // n*CAP

    size_t need = ((size_t)n * (2 + 64 * 3 + CAP) + 16 + MAX_OVF) * 4;
    bool fast = ws_size >= need;

    int gb = (n + 63) / 64;
    int gn4 = (n + 3) / 4;

    if (fast) {
        hipMemsetAsync(S, 0, (size_t)n * sizeof(float), stream);
        hipMemsetAsync(cnt, 0, (size_t)n * sizeof(int), stream);
        hipMemsetAsync(ovfc, 0, 16 * sizeof(int), stream);
        build_kernel<<<(E + 255) / 256, 256, 0, stream>>>(row, col, imp, S, cnt, bucket, ovf, ovfc, E);

        gemm_dual<32, false><<<gb, 256, 0, stream>>>(x, W1, b1, Wi1, S, bufA, bufB, n);
        gather_agg<<<gn4, 256, 0, stream>>>(cnt, bucket, bufA, bufB, n);
        ovf_scatter<<<16, 256, 0, stream>>>(row, col, ovf, ovfc, bufA, bufB);

        gemm_dual<64, true><<<gb, 256, 0, stream>>>(bufB, W2, b2, Wi2, S, bufC, bufA, n);
        gather_agg<<<gn4, 256, 0, stream>>>(cnt, bucket, bufC, bufA, n);
        ovf_scatter<<<16, 256, 0, stream>>>(row, col, ovf, ovfc, bufC, bufA);

        gemm_dual<64, true><<<gb, 256, 0, stream>>>(bufA, W3, b3, Wi3, S, bufB, bufC, n);
        gather_agg<<<gn4, 256, 0, stream>>>(cnt, bucket, bufB, bufC, n);
        ovf_scatter<<<16, 256, 0, stream>>>(row, col, ovf, ovfc, bufB, bufC);

        fc_kernel<<<gn4, 256, 0, stream>>>(bufC, Wfc, bfc, (float*)d_out, n);
    } else {
        // R1 atomic path (fits in 77.2MB, proven passing)
        hipMemsetAsync(S, 0, (size_t)n * sizeof(float), stream);
        compute_S_kernel<<<(E + 255) / 256, 256, 0, stream>>>(row, col, imp, S, E);

        gemm_dual<32, false><<<gb, 256, 0, stream>>>(x, W1, b1, Wi1, S, bufA, bufB, n);
        scatter_kernel<<<2048, 256, 0, stream>>>(row, col, bufA, bufB, E);

        gemm_dual<64, true><<<gb, 256, 0, stream>>>(bufB, W2, b2, Wi2, S, bufC, bufA, n);
        scatter_kernel<<<2048, 256, 0, stream>>>(row, col, bufC, bufA, E);

        gemm_dual<64, true><<<gb, 256, 0, stream>>>(bufA, W3, b3, Wi3, S, bufB, bufC, n);
        scatter_kernel<<<2048, 256, 0, stream>>>(row, col, bufB, bufC, E);

        fc_kernel<<<gn4, 256, 0, stream>>>(bufC, Wfc, bfc, (float*)d_out, n);
    }
}

// Round 3
// 441.534 us; speedup vs baseline: 2.7734x; 1.1511x over previous
//
#include <hip/hip_runtime.h>

// ImpedanceAwareGCN on MI355X.
// segment_sum(out[row] + imp[row]*imp_mod[col], col)
//   = scatter_add(out) + S[v]*imp_mod[v],  S[v] = sum_{e: col=v} imp[row[e]].
// R3: (a) build with 4 edges/thread for atomic MLP (was latency-bound, VALUBusy 0.4%);
//     (b) scatter-source features stored bf16 -> gather reads 16B/thread, half traffic.

#define CAP 64           // Poisson(16) tail past 64 ~ 1e-20 per node
#define MAX_OVF 65536

__device__ inline unsigned short f2bf(float f) {   // RNE fp32->bf16
    unsigned u = __float_as_uint(f);
    unsigned r = u + 0x7fffu + ((u >> 16) & 1u);
    return (unsigned short)(r >> 16);
}
__device__ inline float bflo(unsigned u) { return __uint_as_float(u << 16); }
__device__ inline float bfhi(unsigned u) { return __uint_as_float(u & 0xffff0000u); }

// ---------------- build: S, degree, buckets. 4 edges/thread for ILP ----------------
__global__ __launch_bounds__(256) void build4(const int* __restrict__ row,
        const int* __restrict__ col, const float* __restrict__ imp,
        float* __restrict__ S, int* __restrict__ cnt, int* __restrict__ bucket,
        int* __restrict__ ovf, int* __restrict__ ovf_cnt, int E) {
    int base = (blockIdx.x * 256 + threadIdx.x) * 4;
    if (base >= E) return;
    if (base + 4 <= E) {
        int4 r4 = *(const int4*)(row + base);
        int4 v4 = *(const int4*)(col + base);
        float i0 = imp[r4.x], i1 = imp[r4.y], i2 = imp[r4.z], i3 = imp[r4.w];
        atomicAdd(&S[v4.x], i0);
        atomicAdd(&S[v4.y], i1);
        atomicAdd(&S[v4.z], i2);
        atomicAdd(&S[v4.w], i3);
        int p0 = atomicAdd(&cnt[v4.x], 1);
        int p1 = atomicAdd(&cnt[v4.y], 1);
        int p2 = atomicAdd(&cnt[v4.z], 1);
        int p3 = atomicAdd(&cnt[v4.w], 1);
        if (p0 < CAP) bucket[(size_t)v4.x * CAP + p0] = r4.x;
        else { int o = atomicAdd(ovf_cnt, 1); if (o < MAX_OVF) ovf[o] = base; }
        if (p1 < CAP) bucket[(size_t)v4.y * CAP + p1] = r4.y;
        else { int o = atomicAdd(ovf_cnt, 1); if (o < MAX_OVF) ovf[o] = base + 1; }
        if (p2 < CAP) bucket[(size_t)v4.z * CAP + p2] = r4.z;
        else { int o = atomicAdd(ovf_cnt, 1); if (o < MAX_OVF) ovf[o] = base + 2; }
        if (p3 < CAP) bucket[(size_t)v4.w * CAP + p3] = r4.w;
        else { int o = atomicAdd(ovf_cnt, 1); if (o < MAX_OVF) ovf[o] = base + 3; }
    } else {
        for (int e = base; e < E; ++e) {
            int r = row[e], v = col[e];
            atomicAdd(&S[v], imp[r]);
            int p = atomicAdd(&cnt[v], 1);
            if (p < CAP) bucket[(size_t)v * CAP + p] = r;
            else { int o = atomicAdd(ovf_cnt, 1); if (o < MAX_OVF) ovf[o] = e; }
        }
    }
}

// ---------------- Dual GEMM: out_bf16 = act(in)@W+b (bf16), nxt = S*(act(in)@Wi) ----------------
template<int K, bool RELU>
__global__ __launch_bounds__(256) void gemm_dual(const float* __restrict__ in,
        const float* __restrict__ W, const float* __restrict__ b,
        const float* __restrict__ Wi, const float* __restrict__ S,
        unsigned short* __restrict__ outb, float* __restrict__ nxt, int n) {
    __shared__ float Ws[K * 64];
    __shared__ float Wis[K * 64];
    __shared__ float xs[64 * (K + 1)];

    for (int i = threadIdx.x; i < K * 64; i += 256) {
        Ws[i]  = W[i];
        Wis[i] = Wi[i];
    }
    int node0 = blockIdx.x * 64;
    for (int i = threadIdx.x; i < 64 * K; i += 256) {
        int nl = i / K, k = i - nl * K;
        int node = node0 + nl;
        float v = (node < n) ? in[(size_t)node0 * K + i] : 0.f;
        if (RELU) v = (v >= 0.f) ? v : 0.2f * v;
        xs[nl * (K + 1) + k] = v;
    }
    __syncthreads();

    int local = threadIdx.x >> 2;
    int c0    = (threadIdx.x & 3) << 4;
    int node  = node0 + local;

    float acc[16], acci[16];
#pragma unroll
    for (int j = 0; j < 16; ++j) { acc[j] = 0.f; acci[j] = 0.f; }

#pragma unroll 4
    for (int k = 0; k < K; ++k) {
        float xv = xs[local * (K + 1) + k];
        const float* wr  = &Ws[k * 64 + c0];
        const float* wir = &Wis[k * 64 + c0];
#pragma unroll
        for (int j = 0; j < 16; ++j) {
            acc[j]  = fmaf(xv, wr[j],  acc[j]);
            acci[j] = fmaf(xv, wir[j], acci[j]);
        }
    }

    if (node < n) {
        float sv = S[node];
        size_t base = (size_t)node * 64 + c0;
        unsigned w[8];
#pragma unroll
        for (int k = 0; k < 8; ++k) {
            float o0 = acc[2 * k]     + b[c0 + 2 * k];
            float o1 = acc[2 * k + 1] + b[c0 + 2 * k + 1];
            w[k] = (unsigned)f2bf(o0) | ((unsigned)f2bf(o1) << 16);
        }
        *(uint4*)(outb + base)     = make_uint4(w[0], w[1], w[2], w[3]);
        *(uint4*)(outb + base + 8) = make_uint4(w[4], w[5], w[6], w[7]);
#pragma unroll
        for (int j = 0; j < 16; ++j) nxt[base + j] = sv * acci[j];
    }
}

// ---------------- Gather: 8 threads/node, 16B bf16x8 loads, fp32 accumulate ----------------
__global__ __launch_bounds__(256) void gather_agg(const int* __restrict__ cnt,
        const int* __restrict__ bucket, const unsigned short* __restrict__ outb,
        float* __restrict__ nxt, int n) {
    int t = threadIdx.x;
    int v = blockIdx.x * 32 + (t >> 3);
    if (v >= n) return;
    int sub = t & 7;                       // channel group: [8*sub, 8*sub+8)
    int deg = cnt[v]; if (deg > CAP) deg = CAP;

    float* np = nxt + (size_t)v * 64 + sub * 8;
    float4 n0 = *(float4*)np;
    float4 n1 = *(float4*)(np + 4);
    float acc[8] = {n0.x, n0.y, n0.z, n0.w, n1.x, n1.y, n1.z, n1.w};

    const int* bk = bucket + (size_t)v * CAP;
    int i = 0;
    for (; i + 4 <= deg; i += 4) {
        int4 rr = *(const int4*)(bk + i);   // broadcast across the 8-thread group
        uint4 a0 = *(const uint4*)(outb + (size_t)rr.x * 64 + sub * 8);
        uint4 a1 = *(const uint4*)(outb + (size_t)rr.y * 64 + sub * 8);
        uint4 a2 = *(const uint4*)(outb + (size_t)rr.z * 64 + sub * 8);
        uint4 a3 = *(const uint4*)(outb + (size_t)rr.w * 64 + sub * 8);
        acc[0] += bflo(a0.x) + bflo(a1.x) + bflo(a2.x) + bflo(a3.x);
        acc[1] += bfhi(a0.x) + bfhi(a1.x) + bfhi(a2.x) + bfhi(a3.x);
        acc[2] += bflo(a0.y) + bflo(a1.y) + bflo(a2.y) + bflo(a3.y);
        acc[3] += bfhi(a0.y) + bfhi(a1.y) + bfhi(a2.y) + bfhi(a3.y);
        acc[4] += bflo(a0.z) + bflo(a1.z) + bflo(a2.z) + bflo(a3.z);
        acc[5] += bfhi(a0.z) + bfhi(a1.z) + bfhi(a2.z) + bfhi(a3.z);
        acc[6] += bflo(a0.w) + bflo(a1.w) + bflo(a2.w) + bflo(a3.w);
        acc[7] += bfhi(a0.w) + bfhi(a1.w) + bfhi(a2.w) + bfhi(a3.w);
    }
    for (; i < deg; ++i) {
        int r = bk[i];
        uint4 a = *(const uint4*)(outb + (size_t)r * 64 + sub * 8);
        acc[0] += bflo(a.x); acc[1] += bfhi(a.x);
        acc[2] += bflo(a.y); acc[3] += bfhi(a.y);
        acc[4] += bflo(a.z); acc[5] += bfhi(a.z);
        acc[6] += bflo(a.w); acc[7] += bfhi(a.w);
    }
    *(float4*)np       = make_float4(acc[0], acc[1], acc[2], acc[3]);
    *(float4*)(np + 4) = make_float4(acc[4], acc[5], acc[6], acc[7]);
}

// ---------------- Overflow fallback (expected empty; imp-part covered by S) ----------------
__global__ void ovf_scatter(const int* __restrict__ row, const int* __restrict__ col,
        const int* __restrict__ ovf, const int* __restrict__ ovf_cnt,
        const unsigned short* __restrict__ outb, float* __restrict__ nxt) {
    int m = *ovf_cnt; if (m > MAX_OVF) m = MAX_OVF;
    int tid = blockIdx.x * blockDim.x + threadIdx.x;
    for (int t = tid; t < m * 64; t += gridDim.x * blockDim.x) {
        int e = ovf[t >> 6]; int c = t & 63;
        int r = row[e], v = col[e];
        unsigned u = outb[(size_t)r * 64 + c];
        atomicAdd(&nxt[(size_t)v * 64 + c], __uint_as_float(u << 16));
    }
}

// ---------------- FC head ----------------
__global__ __launch_bounds__(256) void fc_kernel(const float* __restrict__ h,
        const float* __restrict__ Wfc, const float* __restrict__ bfc,
        float* __restrict__ o, int n) {
    int node = blockIdx.x * 4 + (threadIdx.x >> 6);
    int lane = threadIdx.x & 63;
    float v = 0.f;
    if (node < n) v = h[(size_t)node * 64 + lane] * Wfc[lane];
#pragma unroll
    for (int off = 32; off; off >>= 1) v += __shfl_down(v, off, 64);
    if (node < n && lane == 0) o[node] = v + bfc[0];
}

extern "C" void kernel_launch(void* const* d_in, const int* in_sizes, int n_in,
                              void* d_out, int out_size, void* d_ws, size_t ws_size,
                              hipStream_t stream) {
    const float* x   = (const float*)d_in[0];
    const int*   ei  = (const int*)d_in[1];
    const float* imp = (const float*)d_in[2];
    const float* W1  = (const float*)d_in[3];
    const float* b1  = (const float*)d_in[4];
    const float* Wi1 = (const float*)d_in[5];
    const float* W2  = (const float*)d_in[6];
    const float* b2  = (const float*)d_in[7];
    const float* Wi2 = (const float*)d_in[8];
    const float* W3  = (const float*)d_in[9];
    const float* b3  = (const float*)d_in[10];
    const float* Wi3 = (const float*)d_in[11];
    const float* Wfc = (const float*)d_in[12];
    const float* bfc = (const float*)d_in[13];

    int n = in_sizes[0] / 32;      // 100000
    int E = in_sizes[1] / 2;       // 1600000
    const int* row = ei;
    const int* col = ei + E;

    // workspace layout (fp32 words): ~90.7 MB total (103.2 MB proven available)
    float*          S      = (float*)d_ws;                         // n
    int*            cnt    = (int*)(S + n);                        // n
    float*          bufA   = (float*)(cnt + n);                    // n*64
    float*          bufB   = bufA + (size_t)n * 64;                // n*64
    unsigned short* outb   = (unsigned short*)(bufB + (size_t)n * 64); // n*64 bf16
    int*            ovfc   = (int*)(outb + (size_t)n * 64);        // 16
    int*            ovf    = ovfc + 16;                            // MAX_OVF
    int*            bucket = ovf + MAX_OVF;                        // n*CAP

    hipMemsetAsync(S, 0, (size_t)n * sizeof(float), stream);
    hipMemsetAsync(cnt, 0, (size_t)n * sizeof(int), stream);
    hipMemsetAsync(ovfc, 0, 16 * sizeof(int), stream);
    build4<<<(E + 1023) / 1024, 256, 0, stream>>>(row, col, imp, S, cnt, bucket, ovf, ovfc, E);

    int gb  = (n + 63) / 64;    // gemm blocks
    int gg  = (n + 31) / 32;    // gather blocks
    int gn4 = (n + 3) / 4;      // fc blocks

    // Layer 1 (K=32)
    gemm_dual<32, false><<<gb, 256, 0, stream>>>(x, W1, b1, Wi1, S, outb, bufB, n);
    gather_agg<<<gg, 256, 0, stream>>>(cnt, bucket, outb, bufB, n);
    ovf_scatter<<<16, 256, 0, stream>>>(row, col, ovf, ovfc, outb, bufB);

    // Layer 2 (K=64, leaky-relu input)
    gemm_dual<64, true><<<gb, 256, 0, stream>>>(bufB, W2, b2, Wi2, S, outb, bufA, n);
    gather_agg<<<gg, 256, 0, stream>>>(cnt, bucket, outb, bufA, n);
    ovf_scatter<<<16, 256, 0, stream>>>(row, col, ovf, ovfc, outb, bufA);

    // Layer 3 (K=64, leaky-relu input)
    gemm_dual<64, true><<<gb, 256, 0, stream>>>(bufA, W3, b3, Wi3, S, outb, bufB, n);
    gather_agg<<<gg, 256, 0, stream>>>(cnt, bucket, outb, bufB, n);
    ovf_scatter<<<16, 256, 0, stream>>>(row, col, ovf, ovfc, outb, bufB);

    // FC head
    fc_kernel<<<gn4, 256, 0, stream>>>(bufB, Wfc, bfc, (float*)d_out, n);
}

// Round 4
// 400.808 us; speedup vs baseline: 3.0552x; 1.1016x over previous
//
#include <hip/hip_runtime.h>

// ImpedanceAwareGCN on MI355X.
// segment_sum(out[row] + imp[row]*imp_mod[col], col)
//   = scatter_add(out) + S[v]*imp_mod[v],  S[v] = sum_{e: col=v} imp[row[e]].
// R4: build reduced to 2 scattered ops/edge (cnt atomic + bucket store);
//     S computed in a post-pass from buckets (coalesced bucket reads +
//     L2-resident imp gathers). Gather stays bf16 (R3, proven).

#define CAP 64           // Poisson(16) tail past 64 ~ 1e-18 per node
#define MAX_OVF 65536

__device__ inline unsigned short f2bf(float f) {   // RNE fp32->bf16
    unsigned u = __float_as_uint(f);
    unsigned r = u + 0x7fffu + ((u >> 16) & 1u);
    return (unsigned short)(r >> 16);
}
__device__ inline float bflo(unsigned u) { return __uint_as_float(u << 16); }
__device__ inline float bfhi(unsigned u) { return __uint_as_float(u & 0xffff0000u); }

// ---------------- build: degree + buckets only. 1 edge/thread, 2 scattered ops ----------------
__global__ __launch_bounds__(256) void build2(const int* __restrict__ row,
        const int* __restrict__ col, int* __restrict__ cnt, int* __restrict__ bucket,
        int* __restrict__ ovf, int* __restrict__ ovf_cnt, int E) {
    int e = blockIdx.x * 256 + threadIdx.x;
    if (e >= E) return;
    int r = row[e], v = col[e];
    int p = atomicAdd(&cnt[v], 1);
    if (p < CAP) bucket[(size_t)v * CAP + p] = r;
    else { int o = atomicAdd(ovf_cnt, 1); if (o < MAX_OVF) ovf[o] = e; }
}

// ---------------- S from buckets: 8 threads/node, coalesced bucket reads ----------------
__global__ __launch_bounds__(256) void sinit(const int* __restrict__ cnt,
        const int* __restrict__ bucket, const float* __restrict__ imp,
        float* __restrict__ S, int n) {
    int t = threadIdx.x;
    int v = blockIdx.x * 32 + (t >> 3);
    if (v >= n) return;
    int sub = t & 7;
    int deg = cnt[v]; if (deg > CAP) deg = CAP;
    const int* bk = bucket + (size_t)v * CAP;
    float s = 0.f;
    for (int i = sub; i < deg; i += 8) s += imp[bk[i]];   // imp is L2-resident (400KB)
    s += __shfl_down(s, 4, 8);
    s += __shfl_down(s, 2, 8);
    s += __shfl_down(s, 1, 8);
    if (sub == 0) S[v] = s;
}

// S patch for bucket-overflow edges (expected m == 0). Runs AFTER sinit.
__global__ void s_ovf(const int* __restrict__ row, const int* __restrict__ col,
        const int* __restrict__ ovf, const int* __restrict__ ovf_cnt,
        const float* __restrict__ imp, float* __restrict__ S) {
    int m = *ovf_cnt; if (m > MAX_OVF) m = MAX_OVF;
    for (int i = blockIdx.x * blockDim.x + threadIdx.x; i < m; i += gridDim.x * blockDim.x) {
        int e = ovf[i];
        atomicAdd(&S[col[e]], imp[row[e]]);
    }
}

// ---------------- Dual GEMM: outb = bf16(act(in)@W+b), nxt = S*(act(in)@Wi) ----------------
template<int K, bool RELU>
__global__ __launch_bounds__(256) void gemm_dual(const float* __restrict__ in,
        const float* __restrict__ W, const float* __restrict__ b,
        const float* __restrict__ Wi, const float* __restrict__ S,
        unsigned short* __restrict__ outb, float* __restrict__ nxt, int n) {
    __shared__ float Ws[K * 64];
    __shared__ float Wis[K * 64];
    __shared__ float xs[64 * (K + 1)];

    for (int i = threadIdx.x; i < K * 64; i += 256) {
        Ws[i]  = W[i];
        Wis[i] = Wi[i];
    }
    int node0 = blockIdx.x * 64;
    for (int i = threadIdx.x; i < 64 * K; i += 256) {
        int nl = i / K, k = i - nl * K;
        int node = node0 + nl;
        float v = (node < n) ? in[(size_t)node0 * K + i] : 0.f;
        if (RELU) v = (v >= 0.f) ? v : 0.2f * v;
        xs[nl * (K + 1) + k] = v;
    }
    __syncthreads();

    int local = threadIdx.x >> 2;
    int c0    = (threadIdx.x & 3) << 4;
    int node  = node0 + local;

    float acc[16], acci[16];
#pragma unroll
    for (int j = 0; j < 16; ++j) { acc[j] = 0.f; acci[j] = 0.f; }

#pragma unroll 4
    for (int k = 0; k < K; ++k) {
        float xv = xs[local * (K + 1) + k];
        const float* wr  = &Ws[k * 64 + c0];
        const float* wir = &Wis[k * 64 + c0];
#pragma unroll
        for (int j = 0; j < 16; ++j) {
            acc[j]  = fmaf(xv, wr[j],  acc[j]);
            acci[j] = fmaf(xv, wir[j], acci[j]);
        }
    }

    if (node < n) {
        float sv = S[node];
        size_t base = (size_t)node * 64 + c0;
        unsigned w[8];
#pragma unroll
        for (int k = 0; k < 8; ++k) {
            float o0 = acc[2 * k]     + b[c0 + 2 * k];
            float o1 = acc[2 * k + 1] + b[c0 + 2 * k + 1];
            w[k] = (unsigned)f2bf(o0) | ((unsigned)f2bf(o1) << 16);
        }
        *(uint4*)(outb + base)     = make_uint4(w[0], w[1], w[2], w[3]);
        *(uint4*)(outb + base + 8) = make_uint4(w[4], w[5], w[6], w[7]);
#pragma unroll
        for (int j = 0; j < 16; ++j) nxt[base + j] = sv * acci[j];
    }
}

// ---------------- Gather: 8 threads/node, 16B bf16x8 loads, fp32 accumulate ----------------
__global__ __launch_bounds__(256) void gather_agg(const int* __restrict__ cnt,
        const int* __restrict__ bucket, const unsigned short* __restrict__ outb,
        float* __restrict__ nxt, int n) {
    int t = threadIdx.x;
    int v = blockIdx.x * 32 + (t >> 3);
    if (v >= n) return;
    int sub = t & 7;                       // channel group: [8*sub, 8*sub+8)
    int deg = cnt[v]; if (deg > CAP) deg = CAP;

    float* np = nxt + (size_t)v * 64 + sub * 8;
    float4 n0 = *(float4*)np;
    float4 n1 = *(float4*)(np + 4);
    float acc[8] = {n0.x, n0.y, n0.z, n0.w, n1.x, n1.y, n1.z, n1.w};

    const int* bk = bucket + (size_t)v * CAP;
    int i = 0;
    for (; i + 4 <= deg; i += 4) {
        int4 rr = *(const int4*)(bk + i);   // broadcast within 8-thread group
        uint4 a0 = *(const uint4*)(outb + (size_t)rr.x * 64 + sub * 8);
        uint4 a1 = *(const uint4*)(outb + (size_t)rr.y * 64 + sub * 8);
        uint4 a2 = *(const uint4*)(outb + (size_t)rr.z * 64 + sub * 8);
        uint4 a3 = *(const uint4*)(outb + (size_t)rr.w * 64 + sub * 8);
        acc[0] += bflo(a0.x) + bflo(a1.x) + bflo(a2.x) + bflo(a3.x);
        acc[1] += bfhi(a0.x) + bfhi(a1.x) + bfhi(a2.x) + bfhi(a3.x);
        acc[2] += bflo(a0.y) + bflo(a1.y) + bflo(a2.y) + bflo(a3.y);
        acc[3] += bfhi(a0.y) + bfhi(a1.y) + bfhi(a2.y) + bfhi(a3.y);
        acc[4] += bflo(a0.z) + bflo(a1.z) + bflo(a2.z) + bflo(a3.z);
        acc[5] += bfhi(a0.z) + bfhi(a1.z) + bfhi(a2.z) + bfhi(a3.z);
        acc[6] += bflo(a0.w) + bflo(a1.w) + bflo(a2.w) + bflo(a3.w);
        acc[7] += bfhi(a0.w) + bfhi(a1.w) + bfhi(a2.w) + bfhi(a3.w);
    }
    for (; i < deg; ++i) {
        int r = bk[i];
        uint4 a = *(const uint4*)(outb + (size_t)r * 64 + sub * 8);
        acc[0] += bflo(a.x); acc[1] += bfhi(a.x);
        acc[2] += bflo(a.y); acc[3] += bfhi(a.y);
        acc[4] += bflo(a.z); acc[5] += bfhi(a.z);
        acc[6] += bflo(a.w); acc[7] += bfhi(a.w);
    }
    *(float4*)np       = make_float4(acc[0], acc[1], acc[2], acc[3]);
    *(float4*)(np + 4) = make_float4(acc[4], acc[5], acc[6], acc[7]);
}

// ---------------- Overflow fallback for feature part (expected empty) ----------------
__global__ void ovf_scatter(const int* __restrict__ row, const int* __restrict__ col,
        const int* __restrict__ ovf, const int* __restrict__ ovf_cnt,
        const unsigned short* __restrict__ outb, float* __restrict__ nxt) {
    int m = *ovf_cnt; if (m > MAX_OVF) m = MAX_OVF;
    int tid = blockIdx.x * blockDim.x + threadIdx.x;
    for (int t = tid; t < m * 64; t += gridDim.x * blockDim.x) {
        int e = ovf[t >> 6]; int c = t & 63;
        int r = row[e], v = col[e];
        unsigned u = outb[(size_t)r * 64 + c];
        atomicAdd(&nxt[(size_t)v * 64 + c], __uint_as_float(u << 16));
    }
}

// ---------------- FC head ----------------
__global__ __launch_bounds__(256) void fc_kernel(const float* __restrict__ h,
        const float* __restrict__ Wfc, const float* __restrict__ bfc,
        float* __restrict__ o, int n) {
    int node = blockIdx.x * 4 + (threadIdx.x >> 6);
    int lane = threadIdx.x & 63;
    float v = 0.f;
    if (node < n) v = h[(size_t)node * 64 + lane] * Wfc[lane];
#pragma unroll
    for (int off = 32; off; off >>= 1) v += __shfl_down(v, off, 64);
    if (node < n && lane == 0) o[node] = v + bfc[0];
}

extern "C" void kernel_launch(void* const* d_in, const int* in_sizes, int n_in,
                              void* d_out, int out_size, void* d_ws, size_t ws_size,
                              hipStream_t stream) {
    const float* x   = (const float*)d_in[0];
    const int*   ei  = (const int*)d_in[1];
    const float* imp = (const float*)d_in[2];
    const float* W1  = (const float*)d_in[3];
    const float* b1  = (const float*)d_in[4];
    const float* Wi1 = (const float*)d_in[5];
    const float* W2  = (const float*)d_in[6];
    const float* b2  = (const float*)d_in[7];
    const float* Wi2 = (const float*)d_in[8];
    const float* W3  = (const float*)d_in[9];
    const float* b3  = (const float*)d_in[10];
    const float* Wi3 = (const float*)d_in[11];
    const float* Wfc = (const float*)d_in[12];
    const float* bfc = (const float*)d_in[13];

    int n = in_sizes[0] / 32;      // 100000
    int E = in_sizes[1] / 2;       // 1600000
    const int* row = ei;
    const int* col = ei + E;

    // workspace layout (~90.7 MB; 103.2 MB proven available)
    float*          S      = (float*)d_ws;                         // n
    int*            cnt    = (int*)(S + n);                        // n
    float*          bufA   = (float*)(cnt + n);                    // n*64
    float*          bufB   = bufA + (size_t)n * 64;                // n*64
    unsigned short* outb   = (unsigned short*)(bufB + (size_t)n * 64); // n*64 bf16
    int*            ovfc   = (int*)(outb + (size_t)n * 64);        // 16
    int*            ovf    = ovfc + 16;                            // MAX_OVF
    int*            bucket = ovf + MAX_OVF;                        // n*CAP

    hipMemsetAsync(cnt, 0, (size_t)n * sizeof(int), stream);
    hipMemsetAsync(ovfc, 0, 16 * sizeof(int), stream);
    build2<<<(E + 255) / 256, 256, 0, stream>>>(row, col, cnt, bucket, ovf, ovfc, E);

    int gb  = (n + 63) / 64;    // gemm blocks
    int gg  = (n + 31) / 32;    // gather / sinit blocks
    int gn4 = (n + 3) / 4;      // fc blocks

    sinit<<<gg, 256, 0, stream>>>(cnt, bucket, imp, S, n);
    s_ovf<<<4, 256, 0, stream>>>(row, col, ovf, ovfc, imp, S);

    // Layer 1 (K=32)
    gemm_dual<32, false><<<gb, 256, 0, stream>>>(x, W1, b1, Wi1, S, outb, bufB, n);
    gather_agg<<<gg, 256, 0, stream>>>(cnt, bucket, outb, bufB, n);
    ovf_scatter<<<16, 256, 0, stream>>>(row, col, ovf, ovfc, outb, bufB);

    // Layer 2 (K=64, leaky-relu input)
    gemm_dual<64, true><<<gb, 256, 0, stream>>>(bufB, W2, b2, Wi2, S, outb, bufA, n);
    gather_agg<<<gg, 256, 0, stream>>>(cnt, bucket, outb, bufA, n);
    ovf_scatter<<<16, 256, 0, stream>>>(row, col, ovf, ovfc, outb, bufA);

    // Layer 3 (K=64, leaky-relu input)
    gemm_dual<64, true><<<gb, 256, 0, stream>>>(bufA, W3, b3, Wi3, S, outb, bufB, n);
    gather_agg<<<gg, 256, 0, stream>>>(cnt, bucket, outb, bufB, n);
    ovf_scatter<<<16, 256, 0, stream>>>(row, col, ovf, ovfc, outb, bufB);

    // FC head
    fc_kernel<<<gn4, 256, 0, stream>>>(bufB, Wfc, bfc, (float*)d_out, n);
}

// Round 7
// 366.894 us; speedup vs baseline: 3.3376x; 1.0924x over previous
//
#include <hip/hip_runtime.h>

// ImpedanceAwareGCN on MI355X.
// segment_sum(out[row] + imp[row]*imp_mod[col], col)
//   = scatter_add(out) + S[v]*imp_mod[v],  S[v] = sum_{e: col=v} imp[row[e]].
// R7: CSR build as THREE passes (count -> prefix -> scatter) fixing R5/R6's
// fatal bug: the fused phase-A reserved offsets relative to bin-local counters
// without the (not-yet-known) segment bases, so bins overlapped and phase B
// read 0xAA poison -> negative row ids -> HSA fault.

#define BINW    128          // nodes per bin (bin = col >> 7)
#define CHUNK   4096         // edges per binning block
#define BINCAP  3072         // Phase-B LDS edge cap (mean 2046, +22 sigma)

__device__ inline unsigned short f2bf(float f) {   // RNE fp32->bf16
    unsigned u = __float_as_uint(f);
    unsigned r = u + 0x7fffu + ((u >> 16) & 1u);
    return (unsigned short)(r >> 16);
}
__device__ inline float bflo(unsigned u) { return __uint_as_float(u << 16); }
__device__ inline float bfhi(unsigned u) { return __uint_as_float(u & 0xffff0000u); }

// ---------------- Pass A1: per-bin histogram ----------------
__global__ __launch_bounds__(256) void bin_count(const int* __restrict__ col,
        int* __restrict__ binCnt, int E, int nbin) {
    __shared__ int hist[1024];
    int e0 = blockIdx.x * CHUNK;
    int cnt = E - e0; if (cnt > CHUNK) cnt = CHUNK;
    if (cnt <= 0) return;
    int tid = threadIdx.x;
    for (int b = tid; b < nbin; b += 256) hist[b] = 0;
    __syncthreads();
    for (int i = tid; i < cnt; i += 256) atomicAdd(&hist[col[e0 + i] >> 7], 1);
    __syncthreads();
    for (int b = tid; b < nbin; b += 256)
        if (hist[b]) atomicAdd(&binCnt[b], hist[b]);
}

// ---------------- Prefix: binBase = exclusive scan, zero cursors ----------------
__global__ __launch_bounds__(1024) void bin_prefix(const int* __restrict__ binCnt,
        int* __restrict__ binBase, int* __restrict__ cursor,
        int* __restrict__ node_ptr, int nbin, int n, int E) {
    __shared__ int sa[1024];
    int tid = threadIdx.x;
    sa[tid] = (tid < nbin) ? binCnt[tid] : 0;
    __syncthreads();
    for (int d = 1; d < 1024; d <<= 1) {
        int v = sa[tid] + ((tid >= d) ? sa[tid - d] : 0);
        __syncthreads();
        sa[tid] = v;
        __syncthreads();
    }
    if (tid < nbin) { binBase[tid] = sa[tid] - binCnt[tid]; cursor[tid] = 0; }
    if (tid == 0) node_ptr[n] = E;
}

// ---------------- Pass A2: scatter packed edges into correct bin segments ----------------
__global__ __launch_bounds__(256) void bin_scatter(const int* __restrict__ row,
        const int* __restrict__ col, const int* __restrict__ binBase,
        int* __restrict__ cursor, int* __restrict__ binBuf, int E, int nbin) {
    __shared__ int      wpack[CHUNK];     // (row<<7) | (col&127)
    __shared__ unsigned short wbin[CHUNK];
    __shared__ int      hist[1024];
    __shared__ int      basel[1024];

    int e0 = blockIdx.x * CHUNK;
    int cnt = E - e0; if (cnt > CHUNK) cnt = CHUNK;
    if (cnt <= 0) return;
    int tid = threadIdx.x;

    for (int b = tid; b < nbin; b += 256) hist[b] = 0;
    for (int i = tid; i < cnt; i += 256) {
        int r = row[e0 + i], v = col[e0 + i];
        wpack[i] = (r << 7) | (v & (BINW - 1));
        wbin[i]  = (unsigned short)(v >> 7);
    }
    __syncthreads();
    for (int i = tid; i < cnt; i += 256) atomicAdd(&hist[wbin[i]], 1);
    __syncthreads();
    for (int b = tid; b < nbin; b += 256) {
        int h = hist[b];
        basel[b] = h ? (binBase[b] + atomicAdd(&cursor[b], h)) : 0;  // global segment base
        hist[b] = 0;
    }
    __syncthreads();
    for (int i = tid; i < cnt; i += 256) {
        int b = wbin[i];
        int off = atomicAdd(&hist[b], 1);
        binBuf[basel[b] + off] = wpack[i];
    }
}

// ---------------- Phase B: counting-sort each bin in LDS -> CSR rows, node_ptr, S ----------------
__global__ __launch_bounds__(256) void bin_phaseB(const int* __restrict__ binCnt,
        const int* __restrict__ binBase, const int* __restrict__ binBuf,
        const float* __restrict__ imp, int* __restrict__ rows,
        int* __restrict__ node_ptr, float* __restrict__ S, int n) {
    __shared__ int ein[BINCAP];
    __shared__ int sorted[BINCAP];
    __shared__ int dhist[BINW];
    __shared__ int dpre[BINW];
    __shared__ int doff[BINW];

    int b = blockIdx.x;
    int base = binBase[b];
    int cnt = binCnt[b]; if (cnt > BINCAP) cnt = BINCAP;   // +22 sigma, never hit
    int tid = threadIdx.x;
    int v0 = b << 7;

    if (tid < BINW) { dhist[tid] = 0; doff[tid] = 0; }
    for (int i = tid; i < cnt; i += 256) ein[i] = binBuf[base + i];
    __syncthreads();
    for (int i = tid; i < cnt; i += 256) atomicAdd(&dhist[ein[i] & (BINW - 1)], 1);
    __syncthreads();
    if (tid < BINW) dpre[tid] = dhist[tid];
    __syncthreads();
    for (int d = 1; d < BINW; d <<= 1) {
        int v = 0;
        if (tid < BINW) v = dpre[tid] + ((tid >= d) ? dpre[tid - d] : 0);
        __syncthreads();
        if (tid < BINW) dpre[tid] = v;
        __syncthreads();
    }
    if (tid < BINW) {
        int v = v0 + tid;
        if (v < n) node_ptr[v] = base + dpre[tid] - dhist[tid];
    }
    __syncthreads();
    for (int i = tid; i < cnt; i += 256) {
        int w = ein[i];
        int j = w & (BINW - 1);
        int off = atomicAdd(&doff[j], 1);
        sorted[dpre[j] - dhist[j] + off] = w >> 7;     // row id
    }
    __syncthreads();
    for (int i = tid; i < cnt; i += 256) rows[base + i] = sorted[i];
    // S[v] = sum imp[row] over the node's edges (imp is L2-resident, 400KB)
    if (tid < BINW) {
        int v = v0 + tid;
        if (v < n) {
            int a = dpre[tid] - dhist[tid], e = dpre[tid];
            float s0 = 0.f, s1 = 0.f;
            int i = a;
            for (; i + 2 <= e; i += 2) { s0 += imp[sorted[i]]; s1 += imp[sorted[i + 1]]; }
            if (i < e) s0 += imp[sorted[i]];
            S[v] = s0 + s1;
        }
    }
}

// ---------------- Dual GEMM: outb = bf16(act(in)@W+b), nxt = S*(act(in)@Wi) ----------------
template<int K, bool RELU>
__global__ __launch_bounds__(256) void gemm_dual(const float* __restrict__ in,
        const float* __restrict__ W, const float* __restrict__ b,
        const float* __restrict__ Wi, const float* __restrict__ S,
        unsigned short* __restrict__ outb, float* __restrict__ nxt, int n) {
    __shared__ float Ws[K * 64];
    __shared__ float Wis[K * 64];
    __shared__ float xs[64 * (K + 1)];

    for (int i = threadIdx.x; i < K * 64; i += 256) {
        Ws[i]  = W[i];
        Wis[i] = Wi[i];
    }
    int node0 = blockIdx.x * 64;
    for (int i = threadIdx.x; i < 64 * K; i += 256) {
        int nl = i / K, k = i - nl * K;
        int node = node0 + nl;
        float v = (node < n) ? in[(size_t)node0 * K + i] : 0.f;
        if (RELU) v = (v >= 0.f) ? v : 0.2f * v;
        xs[nl * (K + 1) + k] = v;
    }
    __syncthreads();

    int local = threadIdx.x >> 2;
    int c0    = (threadIdx.x & 3) << 4;
    int node  = node0 + local;

    float acc[16], acci[16];
#pragma unroll
    for (int j = 0; j < 16; ++j) { acc[j] = 0.f; acci[j] = 0.f; }

#pragma unroll 4
    for (int k = 0; k < K; ++k) {
        float xv = xs[local * (K + 1) + k];
        const float* wr  = &Ws[k * 64 + c0];
        const float* wir = &Wis[k * 64 + c0];
#pragma unroll
        for (int j = 0; j < 16; ++j) {
            acc[j]  = fmaf(xv, wr[j],  acc[j]);
            acci[j] = fmaf(xv, wir[j], acci[j]);
        }
    }

    if (node < n) {
        float sv = S[node];
        size_t base = (size_t)node * 64 + c0;
        unsigned w[8];
#pragma unroll
        for (int k = 0; k < 8; ++k) {
            float o0 = acc[2 * k]     + b[c0 + 2 * k];
            float o1 = acc[2 * k + 1] + b[c0 + 2 * k + 1];
            w[k] = (unsigned)f2bf(o0) | ((unsigned)f2bf(o1) << 16);
        }
        *(uint4*)(outb + base)     = make_uint4(w[0], w[1], w[2], w[3]);
        *(uint4*)(outb + base + 8) = make_uint4(w[4], w[5], w[6], w[7]);
#pragma unroll
        for (int j = 0; j < 16; ++j) nxt[base + j] = sv * acci[j];
    }
}

// ---------------- Gather (CSR): 8 threads/node, bf16x8 row loads, fp32 accumulate ----------------
__global__ __launch_bounds__(256) void gather_agg(const int* __restrict__ node_ptr,
        const int* __restrict__ rows, const unsigned short* __restrict__ outb,
        float* __restrict__ nxt, int n) {
    int t = threadIdx.x;
    int v = blockIdx.x * 32 + (t >> 3);
    if (v >= n) return;
    int sub = t & 7;                       // channel group: [8*sub, 8*sub+8)
    int p0 = node_ptr[v], p1 = node_ptr[v + 1];

    float* np = nxt + (size_t)v * 64 + sub * 8;
    float4 n0 = *(float4*)np;
    float4 n1 = *(float4*)(np + 4);
    float acc[8] = {n0.x, n0.y, n0.z, n0.w, n1.x, n1.y, n1.z, n1.w};

    int i = p0;
    for (; i + 4 <= p1; i += 4) {
        int r0 = rows[i], r1 = rows[i + 1], r2 = rows[i + 2], r3 = rows[i + 3];
        uint4 a0 = *(const uint4*)(outb + (size_t)r0 * 64 + sub * 8);
        uint4 a1 = *(const uint4*)(outb + (size_t)r1 * 64 + sub * 8);
        uint4 a2 = *(const uint4*)(outb + (size_t)r2 * 64 + sub * 8);
        uint4 a3 = *(const uint4*)(outb + (size_t)r3 * 64 + sub * 8);
        acc[0] += bflo(a0.x) + bflo(a1.x) + bflo(a2.x) + bflo(a3.x);
        acc[1] += bfhi(a0.x) + bfhi(a1.x) + bfhi(a2.x) + bfhi(a3.x);
        acc[2] += bflo(a0.y) + bflo(a1.y) + bflo(a2.y) + bflo(a3.y);
        acc[3] += bfhi(a0.y) + bfhi(a1.y) + bfhi(a2.y) + bfhi(a3.y);
        acc[4] += bflo(a0.z) + bflo(a1.z) + bflo(a2.z) + bflo(a3.z);
        acc[5] += bfhi(a0.z) + bfhi(a1.z) + bfhi(a2.z) + bfhi(a3.z);
        acc[6] += bflo(a0.w) + bflo(a1.w) + bflo(a2.w) + bflo(a3.w);
        acc[7] += bfhi(a0.w) + bfhi(a1.w) + bfhi(a2.w) + bfhi(a3.w);
    }
    for (; i < p1; ++i) {
        int r = rows[i];
        uint4 a = *(const uint4*)(outb + (size_t)r * 64 + sub * 8);
        acc[0] += bflo(a.x); acc[1] += bfhi(a.x);
        acc[2] += bflo(a.y); acc[3] += bfhi(a.y);
        acc[4] += bflo(a.z); acc[5] += bfhi(a.z);
        acc[6] += bflo(a.w); acc[7] += bfhi(a.w);
    }
    *(float4*)np       = make_float4(acc[0], acc[1], acc[2], acc[3]);
    *(float4*)(np + 4) = make_float4(acc[4], acc[5], acc[6], acc[7]);
}

// ---------------- FC head ----------------
__global__ __launch_bounds__(256) void fc_kernel(const float* __restrict__ h,
        const float* __restrict__ Wfc, const float* __restrict__ bfc,
        float* __restrict__ o, int n) {
    int node = blockIdx.x * 4 + (threadIdx.x >> 6);
    int lane = threadIdx.x & 63;
    float v = 0.f;
    if (node < n) v = h[(size_t)node * 64 + lane] * Wfc[lane];
#pragma unroll
    for (int off = 32; off; off >>= 1) v += __shfl_down(v, off, 64);
    if (node < n && lane == 0) o[node] = v + bfc[0];
}

extern "C" void kernel_launch(void* const* d_in, const int* in_sizes, int n_in,
                              void* d_out, int out_size, void* d_ws, size_t ws_size,
                              hipStream_t stream) {
    const float* x   = (const float*)d_in[0];
    const int*   ei  = (const int*)d_in[1];
    const float* imp = (const float*)d_in[2];
    const float* W1  = (const float*)d_in[3];
    const float* b1  = (const float*)d_in[4];
    const float* Wi1 = (const float*)d_in[5];
    const float* W2  = (const float*)d_in[6];
    const float* b2  = (const float*)d_in[7];
    const float* Wi2 = (const float*)d_in[8];
    const float* W3  = (const float*)d_in[9];
    const float* b3  = (const float*)d_in[10];
    const float* Wi3 = (const float*)d_in[11];
    const float* Wfc = (const float*)d_in[12];
    const float* bfc = (const float*)d_in[13];

    int n = in_sizes[0] / 32;      // 100000
    int E = in_sizes[1] / 2;       // 1600000
    const int* row = ei;
    const int* col = ei + E;
    int nbin = (n + BINW - 1) / BINW;   // 782

    // ---- workspace: bump allocator, every region 64B-aligned ----
    size_t off = 0;
    auto alloc = [&](size_t words) {
        size_t cur = off;
        off += (words + 15) & ~(size_t)15;
        return cur;
    };
    int* wsw = (int*)d_ws;
    float*          S        = (float*)(wsw + alloc(n));
    int*            node_ptr = wsw + alloc((size_t)n + 1);
    int*            binCnt   = wsw + alloc(1024);
    int*            binBase  = wsw + alloc(1024);
    int*            cursor   = wsw + alloc(1024);
    int*            binBuf   = wsw + alloc(E);
    int*            rowsA    = wsw + alloc(E);
    float*          bufA     = (float*)(wsw + alloc((size_t)n * 64));
    float*          bufB     = (float*)(wsw + alloc((size_t)n * 64));
    unsigned short* outb     = (unsigned short*)(wsw + alloc((size_t)n * 32));

    int gA = (E + CHUNK - 1) / CHUNK;   // 391 binning blocks

    hipMemsetAsync(binCnt, 0, 1024 * sizeof(int), stream);
    bin_count  <<<gA, 256, 0, stream>>>(col, binCnt, E, nbin);
    bin_prefix <<<1, 1024, 0, stream>>>(binCnt, binBase, cursor, node_ptr, nbin, n, E);
    bin_scatter<<<gA, 256, 0, stream>>>(row, col, binBase, cursor, binBuf, E, nbin);
    bin_phaseB <<<nbin, 256, 0, stream>>>(binCnt, binBase, binBuf, imp, rowsA, node_ptr, S, n);

    int gb = (n + 63) / 64;     // gemm blocks
    int gg = (n + 31) / 32;     // gather blocks
    int gn4 = (n + 3) / 4;      // fc blocks

    // Layer 1 (K=32)
    gemm_dual<32, false><<<gb, 256, 0, stream>>>(x, W1, b1, Wi1, S, outb, bufB, n);
    gather_agg<<<gg, 256, 0, stream>>>(node_ptr, rowsA, outb, bufB, n);

    // Layer 2 (K=64, leaky-relu input)
    gemm_dual<64, true><<<gb, 256, 0, stream>>>(bufB, W2, b2, Wi2, S, outb, bufA, n);
    gather_agg<<<gg, 256, 0, stream>>>(node_ptr, rowsA, outb, bufA, n);

    // Layer 3 (K=64, leaky-relu input)
    gemm_dual<64, true><<<gb, 256, 0, stream>>>(bufA, W3, b3, Wi3, S, outb, bufB, n);
    gather_agg<<<gg, 256, 0, stream>>>(node_ptr, rowsA, outb, bufB, n);

    // FC head
    fc_kernel<<<gn4, 256, 0, stream>>>(bufB, Wfc, bfc, (float*)d_out, n);
}

// Round 8
// 292.334 us; speedup vs baseline: 4.1888x; 1.2550x over previous
//
#include <hip/hip_runtime.h>

// ImpedanceAwareGCN on MI355X.
// segment_sum(out[row] + imp[row]*imp_mod[col], col)
//   = scatter_add(out) + S[v]*imp_mod[v],  S[v] = sum_{e: col=v} imp[row[e]].
// R8: dual GEMM moved to bf16 MFMA (16x16x32). Weights pre-packed once into
// fragment layout in a small L1-resident global table (wpack); A-operand read
// directly from bf16 activations (gather now writes bf16+relu). fp32 gemm was
// LDS-bound at 38% VALU with a 21us FMA floor; MFMA removes both limits.

#define BINW    128          // nodes per bin (bin = col >> 7)
#define CHUNK   4096         // edges per binning block
#define BINCAP  3072         // Phase-B LDS edge cap (mean 2046, +22 sigma)

typedef __attribute__((ext_vector_type(8))) short bf16x8;
typedef __attribute__((ext_vector_type(4))) float f32x4;

__device__ inline unsigned short f2bf(float f) {   // RNE fp32->bf16
    unsigned u = __float_as_uint(f);
    unsigned r = u + 0x7fffu + ((u >> 16) & 1u);
    return (unsigned short)(r >> 16);
}
__device__ inline float bflo(unsigned u) { return __uint_as_float(u << 16); }
__device__ inline float bfhi(unsigned u) { return __uint_as_float(u & 0xffff0000u); }

// ---------------- Pass A1: per-bin histogram ----------------
__global__ __launch_bounds__(256) void bin_count(const int* __restrict__ col,
        int* __restrict__ binCnt, int E, int nbin) {
    __shared__ int hist[1024];
    int e0 = blockIdx.x * CHUNK;
    int cnt = E - e0; if (cnt > CHUNK) cnt = CHUNK;
    if (cnt <= 0) return;
    int tid = threadIdx.x;
    for (int b = tid; b < nbin; b += 256) hist[b] = 0;
    __syncthreads();
    for (int i = tid; i < cnt; i += 256) atomicAdd(&hist[col[e0 + i] >> 7], 1);
    __syncthreads();
    for (int b = tid; b < nbin; b += 256)
        if (hist[b]) atomicAdd(&binCnt[b], hist[b]);
}

// ---------------- Prefix: binBase = exclusive scan, zero cursors ----------------
__global__ __launch_bounds__(1024) void bin_prefix(const int* __restrict__ binCnt,
        int* __restrict__ binBase, int* __restrict__ cursor,
        int* __restrict__ node_ptr, int nbin, int n, int E) {
    __shared__ int sa[1024];
    int tid = threadIdx.x;
    sa[tid] = (tid < nbin) ? binCnt[tid] : 0;
    __syncthreads();
    for (int d = 1; d < 1024; d <<= 1) {
        int v = sa[tid] + ((tid >= d) ? sa[tid - d] : 0);
        __syncthreads();
        sa[tid] = v;
        __syncthreads();
    }
    if (tid < nbin) { binBase[tid] = sa[tid] - binCnt[tid]; cursor[tid] = 0; }
    if (tid == 0) node_ptr[n] = E;
}

// ---------------- Pass A2: scatter packed edges into correct bin segments ----------------
__global__ __launch_bounds__(256) void bin_scatter(const int* __restrict__ row,
        const int* __restrict__ col, const int* __restrict__ binBase,
        int* __restrict__ cursor, int* __restrict__ binBuf, int E, int nbin) {
    __shared__ int      wpackl[CHUNK];     // (row<<7) | (col&127)
    __shared__ unsigned short wbin[CHUNK];
    __shared__ int      hist[1024];
    __shared__ int      basel[1024];

    int e0 = blockIdx.x * CHUNK;
    int cnt = E - e0; if (cnt > CHUNK) cnt = CHUNK;
    if (cnt <= 0) return;
    int tid = threadIdx.x;

    for (int b = tid; b < nbin; b += 256) hist[b] = 0;
    for (int i = tid; i < cnt; i += 256) {
        int r = row[e0 + i], v = col[e0 + i];
        wpackl[i] = (r << 7) | (v & (BINW - 1));
        wbin[i]  = (unsigned short)(v >> 7);
    }
    __syncthreads();
    for (int i = tid; i < cnt; i += 256) atomicAdd(&hist[wbin[i]], 1);
    __syncthreads();
    for (int b = tid; b < nbin; b += 256) {
        int h = hist[b];
        basel[b] = h ? (binBase[b] + atomicAdd(&cursor[b], h)) : 0;
        hist[b] = 0;
    }
    __syncthreads();
    for (int i = tid; i < cnt; i += 256) {
        int b = wbin[i];
        int off = atomicAdd(&hist[b], 1);
        binBuf[basel[b] + off] = wpackl[i];
    }
}

// ---------------- Phase B: counting-sort each bin in LDS -> CSR rows, node_ptr, S ----------------
__global__ __launch_bounds__(256) void bin_phaseB(const int* __restrict__ binCnt,
        const int* __restrict__ binBase, const int* __restrict__ binBuf,
        const float* __restrict__ imp, int* __restrict__ rows,
        int* __restrict__ node_ptr, float* __restrict__ S, int n) {
    __shared__ int ein[BINCAP];
    __shared__ int sorted[BINCAP];
    __shared__ int dhist[BINW];
    __shared__ int dpre[BINW];
    __shared__ int doff[BINW];

    int b = blockIdx.x;
    int base = binBase[b];
    int cnt = binCnt[b]; if (cnt > BINCAP) cnt = BINCAP;
    int tid = threadIdx.x;
    int v0 = b << 7;

    if (tid < BINW) { dhist[tid] = 0; doff[tid] = 0; }
    for (int i = tid; i < cnt; i += 256) ein[i] = binBuf[base + i];
    __syncthreads();
    for (int i = tid; i < cnt; i += 256) atomicAdd(&dhist[ein[i] & (BINW - 1)], 1);
    __syncthreads();
    if (tid < BINW) dpre[tid] = dhist[tid];
    __syncthreads();
    for (int d = 1; d < BINW; d <<= 1) {
        int v = 0;
        if (tid < BINW) v = dpre[tid] + ((tid >= d) ? dpre[tid - d] : 0);
        __syncthreads();
        if (tid < BINW) dpre[tid] = v;
        __syncthreads();
    }
    if (tid < BINW) {
        int v = v0 + tid;
        if (v < n) node_ptr[v] = base + dpre[tid] - dhist[tid];
    }
    __syncthreads();
    for (int i = tid; i < cnt; i += 256) {
        int w = ein[i];
        int j = w & (BINW - 1);
        int off = atomicAdd(&doff[j], 1);
        sorted[dpre[j] - dhist[j] + off] = w >> 7;
    }
    __syncthreads();
    for (int i = tid; i < cnt; i += 256) rows[base + i] = sorted[i];
    if (tid < BINW) {
        int v = v0 + tid;
        if (v < n) {
            int a = dpre[tid] - dhist[tid], e = dpre[tid];
            float s0 = 0.f, s1 = 0.f;
            int i = a;
            for (; i + 2 <= e; i += 2) { s0 += imp[sorted[i]]; s1 += imp[sorted[i + 1]]; }
            if (i < e) s0 += imp[sorted[i]];
            S[v] = s0 + s1;
        }
    }
}

// ---------------- x -> bf16 convert (layer-1 A operand) ----------------
__global__ __launch_bounds__(256) void xconv(const float* __restrict__ x,
        unsigned short* __restrict__ xb, long total8) {   // total8 = n*32/8
    long i = (long)blockIdx.x * 256 + threadIdx.x;
    if (i >= total8) return;
    const float4* xp = (const float4*)(x + i * 8);
    float4 a = xp[0], b = xp[1];
    uint4 w = make_uint4(
        (unsigned)f2bf(a.x) | ((unsigned)f2bf(a.y) << 16),
        (unsigned)f2bf(a.z) | ((unsigned)f2bf(a.w) << 16),
        (unsigned)f2bf(b.x) | ((unsigned)f2bf(b.y) << 16),
        (unsigned)f2bf(b.z) | ((unsigned)f2bf(b.w) << 16));
    *(uint4*)(xb + i * 8) = w;
}

// ---------------- weight pack: fragment layout [m][kc][ct][lane][8], bf16 ----------------
// B-frag mapping: col = ct*16 + (lane&15), k = kc*32 + (lane>>4)*8 + e
__global__ __launch_bounds__(256) void wpack_all(
        const float* __restrict__ W1, const float* __restrict__ Wi1,
        const float* __restrict__ W2, const float* __restrict__ Wi2,
        const float* __restrict__ W3, const float* __restrict__ Wi3,
        unsigned short* __restrict__ wf1, unsigned short* __restrict__ wf2,
        unsigned short* __restrict__ wf3) {
    int blk = blockIdx.x;
    const float *W, *Wi; unsigned short* dst; int KC;
    if (blk == 0)      { W = W1; Wi = Wi1; dst = wf1; KC = 1; }
    else if (blk == 1) { W = W2; Wi = Wi2; dst = wf2; KC = 2; }
    else               { W = W3; Wi = Wi3; dst = wf3; KC = 2; }
    int SLOTS = 2 * KC * 4 * 64;
    for (int s = threadIdx.x; s < SLOTS; s += 256) {
        int l  = s & 63;
        int ct = (s >> 6) & 3;
        int kc = (s >> 8) % KC;
        int m  = s / (256 * KC);
        int k   = kc * 32 + ((l >> 4) << 3);
        int c   = ct * 16 + (l & 15);
        const float* src = m ? Wi : W;
        unsigned short t[8];
#pragma unroll
        for (int e = 0; e < 8; ++e) t[e] = f2bf(src[(k + e) * 64 + c]);
        *(uint4*)(dst + (size_t)s * 8) = make_uint4(
            (unsigned)t[0] | ((unsigned)t[1] << 16),
            (unsigned)t[2] | ((unsigned)t[3] << 16),
            (unsigned)t[4] | ((unsigned)t[5] << 16),
            (unsigned)t[6] | ((unsigned)t[7] << 16));
    }
}

// ---------------- MFMA dual GEMM: outb = bf16(in@W+b), nxt = S*(in@Wi) ----------------
// in: bf16 [n][K] (relu pre-applied by producer). wave = 16 nodes x 64 cols.
template<int K>
__global__ __launch_bounds__(256) void gemm_mfma(
        const unsigned short* __restrict__ hb, const unsigned short* __restrict__ wf,
        const float* __restrict__ bias, const float* __restrict__ S,
        unsigned short* __restrict__ outb, float* __restrict__ nxt, int n) {
    constexpr int KC = K / 32;
    int lane = threadIdx.x & 63;
    int node0 = blockIdx.x * 64 + (threadIdx.x >> 6) * 16;
    if (node0 >= n) return;

    int arow = node0 + (lane & 15);
    if (arow >= n) arow = n - 1;                       // clamp; result discarded
    const unsigned short* ap = hb + (size_t)arow * K + ((lane >> 4) << 3);

    f32x4 z = {0.f, 0.f, 0.f, 0.f};
    f32x4 accW[4] = {z, z, z, z};
    f32x4 accI[4] = {z, z, z, z};

#pragma unroll
    for (int kc = 0; kc < KC; ++kc) {
        bf16x8 a = *(const bf16x8*)(ap + kc * 32);
#pragma unroll
        for (int ct = 0; ct < 4; ++ct) {
            bf16x8 bw = *(const bf16x8*)(wf + ((((size_t)0 * KC + kc) * 4 + ct) * 64 + lane) * 8);
            bf16x8 bi = *(const bf16x8*)(wf + ((((size_t)1 * KC + kc) * 4 + ct) * 64 + lane) * 8);
            accW[ct] = __builtin_amdgcn_mfma_f32_16x16x32_bf16(a, bw, accW[ct], 0, 0, 0);
            accI[ct] = __builtin_amdgcn_mfma_f32_16x16x32_bf16(a, bi, accI[ct], 0, 0, 0);
        }
    }

    // C/D: col = lane&15 (+ct*16), row = node0 + (lane>>4)*4 + j   [m89-verified]
    int colb = lane & 15;
    int rbase = node0 + ((lane >> 4) << 2);
    float sv[4];
#pragma unroll
    for (int j = 0; j < 4; ++j) {
        int r = rbase + j;
        sv[j] = (r < n) ? S[r] : 0.f;
    }
#pragma unroll
    for (int ct = 0; ct < 4; ++ct) {
        int c = ct * 16 + colb;
        float bb = bias[c];
#pragma unroll
        for (int j = 0; j < 4; ++j) {
            int r = rbase + j;
            if (r < n) {
                outb[(size_t)r * 64 + c] = f2bf(accW[ct][j] + bb);
                nxt [(size_t)r * 64 + c] = sv[j] * accI[ct][j];
            }
        }
    }
}

// ---------------- Gather (CSR): 8 threads/node, bf16x8 loads, fp32 accumulate ----------------
// MODE 0: write bf16 + leaky-relu to hb (feeds next MFMA gemm)
// MODE 1: write fp32 in-place to nxt (feeds FC head)
template<int MODE>
__global__ __launch_bounds__(256) void gather_agg(const int* __restrict__ node_ptr,
        const int* __restrict__ rows, const unsigned short* __restrict__ outb,
        float* __restrict__ nxt, unsigned short* __restrict__ hb, int n) {
    int t = threadIdx.x;
    int v = blockIdx.x * 32 + (t >> 3);
    if (v >= n) return;
    int sub = t & 7;
    int p0 = node_ptr[v], p1 = node_ptr[v + 1];

    float* np = nxt + (size_t)v * 64 + sub * 8;
    float4 n0 = *(float4*)np;
    float4 n1 = *(float4*)(np + 4);
    float acc[8] = {n0.x, n0.y, n0.z, n0.w, n1.x, n1.y, n1.z, n1.w};

    int i = p0;
    for (; i + 4 <= p1; i += 4) {
        int r0 = rows[i], r1 = rows[i + 1], r2 = rows[i + 2], r3 = rows[i + 3];
        uint4 a0 = *(const uint4*)(outb + (size_t)r0 * 64 + sub * 8);
        uint4 a1 = *(const uint4*)(outb + (size_t)r1 * 64 + sub * 8);
        uint4 a2 = *(const uint4*)(outb + (size_t)r2 * 64 + sub * 8);
        uint4 a3 = *(const uint4*)(outb + (size_t)r3 * 64 + sub * 8);
        acc[0] += bflo(a0.x) + bflo(a1.x) + bflo(a2.x) + bflo(a3.x);
        acc[1] += bfhi(a0.x) + bfhi(a1.x) + bfhi(a2.x) + bfhi(a3.x);
        acc[2] += bflo(a0.y) + bflo(a1.y) + bflo(a2.y) + bflo(a3.y);
        acc[3] += bfhi(a0.y) + bfhi(a1.y) + bfhi(a2.y) + bfhi(a3.y);
        acc[4] += bflo(a0.z) + bflo(a1.z) + bflo(a2.z) + bflo(a3.z);
        acc[5] += bfhi(a0.z) + bfhi(a1.z) + bfhi(a2.z) + bfhi(a3.z);
        acc[6] += bflo(a0.w) + bflo(a1.w) + bflo(a2.w) + bflo(a3.w);
        acc[7] += bfhi(a0.w) + bfhi(a1.w) + bfhi(a2.w) + bfhi(a3.w);
    }
    for (; i < p1; ++i) {
        int r = rows[i];
        uint4 a = *(const uint4*)(outb + (size_t)r * 64 + sub * 8);
        acc[0] += bflo(a.x); acc[1] += bfhi(a.x);
        acc[2] += bflo(a.y); acc[3] += bfhi(a.y);
        acc[4] += bflo(a.z); acc[5] += bfhi(a.z);
        acc[6] += bflo(a.w); acc[7] += bfhi(a.w);
    }
    if (MODE == 0) {
        unsigned w[4];
#pragma unroll
        for (int q = 0; q < 4; ++q) {
            float v0 = acc[2 * q], v1 = acc[2 * q + 1];
            v0 = (v0 >= 0.f) ? v0 : 0.2f * v0;
            v1 = (v1 >= 0.f) ? v1 : 0.2f * v1;
            w[q] = (unsigned)f2bf(v0) | ((unsigned)f2bf(v1) << 16);
        }
        *(uint4*)(hb + (size_t)v * 64 + sub * 8) = make_uint4(w[0], w[1], w[2], w[3]);
    } else {
        *(float4*)np       = make_float4(acc[0], acc[1], acc[2], acc[3]);
        *(float4*)(np + 4) = make_float4(acc[4], acc[5], acc[6], acc[7]);
    }
}

// ---------------- FC head ----------------
__global__ __launch_bounds__(256) void fc_kernel(const float* __restrict__ h,
        const float* __restrict__ Wfc, const float* __restrict__ bfc,
        float* __restrict__ o, int n) {
    int node = blockIdx.x * 4 + (threadIdx.x >> 6);
    int lane = threadIdx.x & 63;
    float v = 0.f;
    if (node < n) v = h[(size_t)node * 64 + lane] * Wfc[lane];
#pragma unroll
    for (int off = 32; off; off >>= 1) v += __shfl_down(v, off, 64);
    if (node < n && lane == 0) o[node] = v + bfc[0];
}

extern "C" void kernel_launch(void* const* d_in, const int* in_sizes, int n_in,
                              void* d_out, int out_size, void* d_ws, size_t ws_size,
                              hipStream_t stream) {
    const float* x   = (const float*)d_in[0];
    const int*   ei  = (const int*)d_in[1];
    const float* imp = (const float*)d_in[2];
    const float* W1  = (const float*)d_in[3];
    const float* b1  = (const float*)d_in[4];
    const float* Wi1 = (const float*)d_in[5];
    const float* W2  = (const float*)d_in[6];
    const float* b2  = (const float*)d_in[7];
    const float* Wi2 = (const float*)d_in[8];
    const float* W3  = (const float*)d_in[9];
    const float* b3  = (const float*)d_in[10];
    const float* Wi3 = (const float*)d_in[11];
    const float* Wfc = (const float*)d_in[12];
    const float* bfc = (const float*)d_in[13];

    int n = in_sizes[0] / 32;      // 100000
    int E = in_sizes[1] / 2;       // 1600000
    const int* row = ei;
    const int* col = ei + E;
    int nbin = (n + BINW - 1) / BINW;   // 782

    // ---- workspace: bump allocator, 64B-aligned regions (~71 MB total) ----
    size_t off = 0;
    auto alloc = [&](size_t words) {
        size_t cur = off;
        off += (words + 15) & ~(size_t)15;
        return cur;
    };
    int* wsw = (int*)d_ws;
    float*          S        = (float*)(wsw + alloc(n));
    int*            node_ptr = wsw + alloc((size_t)n + 1);
    int*            binCnt   = wsw + alloc(1024);
    int*            binBase  = wsw + alloc(1024);
    int*            cursor   = wsw + alloc(1024);
    int*            binBuf   = wsw + alloc(E);
    int*            rowsA    = wsw + alloc(E);
    float*          nxt      = (float*)(wsw + alloc((size_t)n * 64));
    unsigned short* outb     = (unsigned short*)(wsw + alloc((size_t)n * 32));
    unsigned short* hb       = (unsigned short*)(wsw + alloc((size_t)n * 32));
    unsigned short* xb       = (unsigned short*)(wsw + alloc((size_t)n * 16));
    unsigned short* wf1      = (unsigned short*)(wsw + alloc(2048));   // 2*1*4*64*8 ushort
    unsigned short* wf2      = (unsigned short*)(wsw + alloc(4096));   // 2*2*4*64*8 ushort
    unsigned short* wf3      = (unsigned short*)(wsw + alloc(4096));

    int gA = (E + CHUNK - 1) / CHUNK;

    hipMemsetAsync(binCnt, 0, 1024 * sizeof(int), stream);
    bin_count  <<<gA, 256, 0, stream>>>(col, binCnt, E, nbin);
    bin_prefix <<<1, 1024, 0, stream>>>(binCnt, binBase, cursor, node_ptr, nbin, n, E);
    bin_scatter<<<gA, 256, 0, stream>>>(row, col, binBase, cursor, binBuf, E, nbin);
    bin_phaseB <<<nbin, 256, 0, stream>>>(binCnt, binBase, binBuf, imp, rowsA, node_ptr, S, n);

    long total8 = (long)n * 32 / 8;
    xconv<<<(int)((total8 + 255) / 256), 256, 0, stream>>>(x, xb, total8);
    wpack_all<<<3, 256, 0, stream>>>(W1, Wi1, W2, Wi2, W3, Wi3, wf1, wf2, wf3);

    int gm = (n + 63) / 64;     // mfma gemm blocks (4 waves x 16 nodes)
    int gg = (n + 31) / 32;     // gather blocks
    int gn4 = (n + 3) / 4;      // fc blocks

    // Layer 1 (K=32, input xb)
    gemm_mfma<32><<<gm, 256, 0, stream>>>(xb, wf1, b1, S, outb, nxt, n);
    gather_agg<0><<<gg, 256, 0, stream>>>(node_ptr, rowsA, outb, nxt, hb, n);

    // Layer 2 (K=64, input hb = relu'd bf16)
    gemm_mfma<64><<<gm, 256, 0, stream>>>(hb, wf2, b2, S, outb, nxt, n);
    gather_agg<0><<<gg, 256, 0, stream>>>(node_ptr, rowsA, outb, nxt, hb, n);

    // Layer 3 (K=64)
    gemm_mfma<64><<<gm, 256, 0, stream>>>(hb, wf3, b3, S, outb, nxt, n);
    gather_agg<1><<<gg, 256, 0, stream>>>(node_ptr, rowsA, outb, nxt, hb, n);

    // FC head
    fc_kernel<<<gn4, 256, 0, stream>>>(nxt, Wfc, bfc, (float*)d_out, n);
}